// Round 5
// baseline (612.618 us; speedup 1.0000x reference)
//
#include <hip/hip_runtime.h>

typedef short  s16x8  __attribute__((ext_vector_type(8)));
typedef float  f32x16 __attribute__((ext_vector_type(16)));
typedef float  f32x2  __attribute__((ext_vector_type(2)));
typedef unsigned short u16x4 __attribute__((ext_vector_type(4)));

#define D_FEAT     256
#define KE         272                  // 256 features + 4 norm slots + 12 zero pad
#define KF         17                   // K fragments of 16 (272/16)
#define N_SAMP     4096
#define N_TRAIN    65536
#define NCHUNK     64
#define CHUNK_ROWS (N_TRAIN / NCHUNK)   // 1024
#define ROWS_ITER  64                   // train rows per iteration (2 at-tiles)
#define NITER      (CHUNK_ROWS / ROWS_ITER) // 16
#define ROW_BYTES  (KE * 2)             // 544
#define BUF_BYTES  (ROWS_ITER * ROW_BYTES)  // 34816; 2 bufs = 68 KiB -> 2 blocks/CU
#define NREGION    (BUF_BYTES / 1024)   // 34 = 2 at-tiles x 17 kf
#define ATILES     (ROWS_ITER / 32)     // 2

__device__ __forceinline__ unsigned short f2bf(float f) {
  unsigned int u = __builtin_bit_cast(unsigned int, f);
  u += 0x7FFFu + ((u >> 16) & 1u);
  return (unsigned short)(u >> 16);
}

// ---------------- prep: fp32 [rows][256] -> bf16 ext [rows][272] ----------------
// ext slots (train): {-n_hi,-n_lo,1,1,0*12}; (sample): {1,1,-n_hi,-n_lo,0*12},
// n=||row||^2/2. GEMM yields t = x.y - ||x||^2/2 - ||y||^2/2 = -d^2/2 directly.
__global__ __launch_bounds__(256) void prep_ext(const float* __restrict__ X,
                                                unsigned short* __restrict__ E,
                                                int nrows, int train_mode) {
  int wv = threadIdx.x >> 6, ln = threadIdx.x & 63;
  int row = blockIdx.x * 4 + wv;
  if (row >= nrows) return;
  const float4* xr = (const float4*)(X + (size_t)row * D_FEAT);
  float4 v = xr[ln];
  float ss = v.x * v.x + v.y * v.y + v.z * v.z + v.w * v.w;
#pragma unroll
  for (int m = 32; m; m >>= 1) ss += __shfl_xor(ss, m);
  float ax = 0.5f * ss;
  u16x4 o;
  o[0] = f2bf(v.x); o[1] = f2bf(v.y); o[2] = f2bf(v.z); o[3] = f2bf(v.w);
  ((u16x4*)(E + (size_t)row * KE))[ln] = o;
  if (ln < 4) {
    u16x4 e = {0, 0, 0, 0};
    if (ln == 0) {
      unsigned short hi = f2bf(ax);
      float hif = __builtin_bit_cast(float, ((unsigned int)hi) << 16);
      unsigned short lo = f2bf(ax - hif);
      unsigned short nhi = (unsigned short)(hi ^ 0x8000u);
      unsigned short nlo = (unsigned short)(lo ^ 0x8000u);
      const unsigned short one = 0x3F80u;
      if (train_mode) { e[0] = nhi; e[1] = nlo; e[2] = one; e[3] = one; }
      else           { e[0] = one; e[1] = one; e[2] = nhi; e[3] = nlo; }
    }
    ((u16x4*)(E + (size_t)row * KE + D_FEAT))[ln] = e;
  }
}

// ---------------- main: 32x32x16 MFMA GEMM + online top-2 ----------------
// 512-thr block (8 waves). Wave owns 64 samples (2 register B-sets x 17 kf).
// LDS: 64 rows x 272 k double-buffered (68 KiB) -> 2 blocks/CU; the two blocks
// are not barrier-coupled, so one block's MFMA phase overlaps the other's LDS/
// VALU phase (de-convoy via TLP, sync template identical to proven round 3).
// 1024-B regions in fragment order: region r = (at r/17, kf r%17),
// lane = (row l&31, k-half l>>5). Stage split: wave w takes r = w+8j (4 or 5).
// Uniform vmcnt(4): with >=4 newest ops being this iter's stage, waiting to <=4
// always fully drains the previous iter's stage (+ any remat loads). Safe.
__global__ __launch_bounds__(512, 4) void topk_gemm(const unsigned short* __restrict__ Aext,
                                                    const unsigned short* __restrict__ Bext,
                                                    f32x2* __restrict__ partials) {
  __shared__ __attribute__((aligned(16))) char smem[2 * BUF_BYTES]; // 68 KiB
  const int tid = threadIdx.x;
  const int wv = tid >> 6, ln = tid & 63;
  const int lc = ln & 31, lh = ln >> 5;
  const int ch = blockIdx.x;   // 0..63 train chunk; same-chunk blocks share an XCD
  const int sb = blockIdx.y;   // 0..7  sample block of 512

  // hoisted sample fragments
  s16x8 sf0[KF], sf1[KF];
  {
    const char* a0 = (const char*)Aext +
                     (size_t)(sb * 512 + wv * 64 + lc) * ROW_BYTES + lh * 16;
#pragma unroll
    for (int kk = 0; kk < KF; kk++) {
      sf0[kk] = *(const s16x8*)(a0 + kk * 32);
      sf1[kk] = *(const s16x8*)(a0 + 32 * ROW_BYTES + kk * 32);
    }
  }

  const char* srcb = (const char*)Bext +
                     ((size_t)ch * CHUNK_ROWS + lc) * ROW_BYTES + lh * 16;

  float b0a = -3.0e38f, b1a = -3.0e38f, b0b = -3.0e38f, b1b = -3.0e38f;

  // wave w stages regions r = w, w+8, w+16, w+24, w+32 (r < 34): 5 for w<2 else 4
  auto stage = [&](int buf, int it) {
    const char* s = srcb + (size_t)it * BUF_BYTES;
    char* bb = smem + buf * BUF_BYTES;
#pragma unroll
    for (int j = 0; j < 5; j++) {
      int r = wv + 8 * j;
      if (r < NREGION) {
        int so = (r / KF) * (32 * ROW_BYTES) + (r % KF) * 32;
        __builtin_amdgcn_global_load_lds(
            (const __attribute__((address_space(1))) void*)(s + so),
            (__attribute__((address_space(3))) void*)(bb + r * 1024),
            16, 0, 0);
      }
    }
  };

  stage(0, 0);

  for (int it = 0; it < NITER; ++it) {
    const int cur = it & 1;
    if (it + 1 < NITER) {
      stage(cur ^ 1, it + 1);
      asm volatile("s_waitcnt vmcnt(4)" ::: "memory");   // drains own prev stage (see note)
    } else {
      asm volatile("s_waitcnt vmcnt(0)" ::: "memory");
    }
    __builtin_amdgcn_s_barrier();                        // buffer cur fully staged
    asm volatile("" ::: "memory");

    const char* lds = smem + cur * BUF_BYTES;
#pragma unroll
    for (int at = 0; at < ATILES; ++at) {
      f32x16 acc0 = {0.f}, acc1 = {0.f};
#pragma unroll
      for (int r = 1; r < 16; r++) { acc0[r] = 0.f; acc1[r] = 0.f; }
#pragma unroll
      for (int kk = 0; kk < KF; kk++) {
        s16x8 av = *(const s16x8*)(lds + at * (KF * 1024) + kk * 1024 + ln * 16);
        acc0 = __builtin_amdgcn_mfma_f32_32x32x16_bf16(av, sf0[kk], acc0, 0, 0, 0);
        acc1 = __builtin_amdgcn_mfma_f32_32x32x16_bf16(av, sf1[kk], acc1, 0, 0, 0);
      }
      // lane holds 16 t = -d^2/2 per sample col; online top-2 via med3 (2 VALU/val)
#pragma unroll
      for (int r = 0; r < 16; r++) {
        float t0 = acc0[r], t1 = acc1[r];
        b1a = __builtin_amdgcn_fmed3f(t0, b0a, b1a); b0a = fmaxf(t0, b0a);
        b1b = __builtin_amdgcn_fmed3f(t1, b0b, b1b); b0b = fmaxf(t1, b0b);
      }
    }
    asm volatile("s_waitcnt lgkmcnt(0)" ::: "memory");   // all ds_reads of buf retired
    __builtin_amdgcn_s_barrier();                        // before anyone overwrites it
    asm volatile("" ::: "memory");
  }

  // lanes l and l+32 hold the same sample col (complementary row sets)
  {
    float o0 = __shfl_xor(b0a, 32), o1 = __shfl_xor(b1a, 32);
    float t = fmaxf(b0a, o0);
    b1a = fmaxf(__builtin_amdgcn_fmed3f(o0, b0a, b1a), o1);
    b0a = t;
    o0 = __shfl_xor(b0b, 32); o1 = __shfl_xor(b1b, 32);
    t = fmaxf(b0b, o0);
    b1b = fmaxf(__builtin_amdgcn_fmed3f(o0, b0b, b1b), o1);
    b0b = t;
  }
  if (lh == 0) {
    int s0 = sb * 512 + wv * 64 + lc;
    f32x2 pa = {b0a, b1a}, pb = {b0b, b1b};
    partials[(size_t)ch * N_SAMP + s0] = pa;
    partials[(size_t)ch * N_SAMP + s0 + 32] = pb;
  }
}

// ---------------- final merge: 32 blocks, distances only ----------------
__global__ __launch_bounds__(128) void reduce_final(const f32x2* __restrict__ partials,
                                                    float* __restrict__ out) {
  int s = blockIdx.x * 128 + threadIdx.x;
  float b0 = -3.0e38f, b1 = -3.0e38f;
#pragma unroll 8
  for (int c = 0; c < NCHUNK; c++) {
    f32x2 p = partials[(size_t)c * N_SAMP + s];
    b1 = __builtin_amdgcn_fmed3f(p[0], b0, b1); b0 = fmaxf(p[0], b0);
    b1 = __builtin_amdgcn_fmed3f(p[1], b0, b1); b0 = fmaxf(p[1], b0);
  }
  out[2 * s]     = sqrtf(fmaxf(-2.0f * b0, 0.0f));
  out[2 * s + 1] = sqrtf(fmaxf(-2.0f * b1, 0.0f));
}

// ---------------- ratio: rescan out, no atomics / no ws state ----------------
__global__ __launch_bounds__(256) void ratio_k(float* __restrict__ out) {
  __shared__ int wsum[4];
  int tid = threadIdx.x;
  int cnt = 0;
#pragma unroll
  for (int rep = 0; rep < 16; ++rep) {
    int s = rep * 256 + tid;
    cnt += (out[2 * s] < (1.0f / 3.0f) * out[2 * s + 1]) ? 1 : 0;
  }
#pragma unroll
  for (int m = 32; m; m >>= 1) cnt += __shfl_xor(cnt, m);
  if ((tid & 63) == 0) wsum[tid >> 6] = cnt;
  __syncthreads();
  if (tid == 0)
    out[2 * N_SAMP] = (float)(wsum[0] + wsum[1] + wsum[2] + wsum[3]) *
                      (1.0f / (float)N_SAMP);
}

extern "C" void kernel_launch(void* const* d_in, const int* in_sizes, int n_in,
                              void* d_out, int out_size, void* d_ws, size_t ws_size,
                              hipStream_t stream) {
  const float* Xs = (const float*)d_in[0];   // X_sample [4096][256]
  const float* Xt = (const float*)d_in[1];   // X_train  [65536][256]
  unsigned short* Bext = (unsigned short*)d_ws;                 // 65536*272 bf16 = 34 MiB
  unsigned short* Aext = Bext + (size_t)N_TRAIN * KE;           // 4096*272 bf16
  f32x2* partials = (f32x2*)(Aext + (size_t)N_SAMP * KE);       // 64*4096 pairs = 2 MiB
  float* out = (float*)d_out;

  prep_ext<<<N_TRAIN / 4, 256, 0, stream>>>(Xt, Bext, N_TRAIN, 1);
  prep_ext<<<N_SAMP / 4, 256, 0, stream>>>(Xs, Aext, N_SAMP, 0);
  topk_gemm<<<dim3(NCHUNK, N_SAMP / 512), 512, 0, stream>>>(Aext, Bext, partials);
  reduce_final<<<N_SAMP / 128, 128, 0, stream>>>(partials, out);
  ratio_k<<<1, 256, 0, stream>>>(out);
}

// Round 6
// 168.789 us; speedup vs baseline: 3.6295x; 3.6295x over previous
//
#include <hip/hip_runtime.h>

typedef int    i32x4  __attribute__((ext_vector_type(4)));
typedef int    i32x8  __attribute__((ext_vector_type(8)));
typedef float  f32x16 __attribute__((ext_vector_type(16)));
typedef float  f32x2  __attribute__((ext_vector_type(2)));
typedef unsigned char u8x4 __attribute__((ext_vector_type(4)));

#define D_FEAT     256
#define N_SAMP     4096
#define N_TRAIN    65536
#define NCHUNK     64
#define CHUNK_ROWS (N_TRAIN / NCHUNK)       // 1024
#define ROWS_ITER  128
#define NITER      (CHUNK_ROWS / ROWS_ITER) // 8
#define ABYTES     (ROWS_ITER * D_FEAT)     // 32768 (A-tile fp8 bytes)
#define NORM_OFF   ABYTES                   // f32 norms region (512 used + 512 pad)
#define BUF_BYTES  (ABYTES + 1024)          // 33792; x2 buffers x2 blocks = 132 KiB/CU

// ---- fp32 -> OCP e4m3fn (RNE, subnormals, clamp 448) ----
__device__ __forceinline__ unsigned char f2fp8(float x) {
  unsigned u = __builtin_bit_cast(unsigned, x);
  unsigned s = (u >> 24) & 0x80u;
  unsigned mag = u & 0x7FFFFFFFu;
  if (mag >= 0x43E80000u) return (unsigned char)(s | 0x7E);  // >=452 -> 448
  unsigned e = mag >> 23;
  if (e >= 121u) {                       // |x| >= 2^-6: normal
    unsigned r = mag + 0x7FFFFu + ((mag >> 20) & 1u);        // RNE at bit 20
    if (r >= 0x43E80000u) return (unsigned char)(s | 0x7E);
    return (unsigned char)(s | (((r >> 23) - 120u) << 3) | ((r >> 20) & 7u));
  }
  float a = __builtin_bit_cast(float, mag) * 512.0f;         // subnormal step 2^-9
  unsigned m = (unsigned)(a + 0.5f);
  if (m >= 8u) return (unsigned char)(s | 0x08u);
  return (unsigned char)(s | m);
}

// ---------------- prep: fp32 [rows][256] -> fp8 [rows][256] + f32 half-norms ----------------
__global__ __launch_bounds__(256) void prep_fp8(const float* __restrict__ X,
                                                unsigned char* __restrict__ F,
                                                float* __restrict__ Nrm, int nrows) {
  int wv = threadIdx.x >> 6, ln = threadIdx.x & 63;
  int row = blockIdx.x * 4 + wv;
  if (row >= nrows) return;
  const float4* xr = (const float4*)(X + (size_t)row * D_FEAT);
  float4 v = xr[ln];
  float ss = v.x * v.x + v.y * v.y + v.z * v.z + v.w * v.w;
#pragma unroll
  for (int m = 32; m; m >>= 1) ss += __shfl_xor(ss, m);
  u8x4 o;
  o[0] = f2fp8(v.x); o[1] = f2fp8(v.y); o[2] = f2fp8(v.z); o[3] = f2fp8(v.w);
  ((u8x4*)(F + (size_t)row * D_FEAT))[ln] = o;
  if (ln == 0) Nrm[row] = 0.5f * ss;     // n = ||row||^2 / 2
}

// ---------------- main: MX-fp8 32x32x64 GEMM + online top-2 ----------------
// 256-thr block (4 waves), wave owns 128 samples = 4 register B-sets x 4 K-chunks
// (128 VGPR). acc = x.y (fp8 dot, scales=1.0); epilogue v = acc - nt (LDS f32),
// final t = v - ns = -d^2/2. LDS: 128 train rows x 256 B fp8 + 512 B norms,
// double-buffered; 1024-B regions in fragment order (region r: at=r>>3,
// kc=(r>>1)&3, h=r&1; lane l holds row at*32+(l&31), bytes kc*64+(l>>5)*32+h*16).
// Proven 2-barrier template, uniform 9 loads/wave/iter, counted vmcnt(9).
__global__ __launch_bounds__(256, 2) void topk_gemm(const unsigned char* __restrict__ Tf8,
                                                    const float* __restrict__ Tnrm,
                                                    const unsigned char* __restrict__ Sf8,
                                                    const float* __restrict__ Snrm,
                                                    f32x2* __restrict__ partials) {
  __shared__ __attribute__((aligned(16))) char smem[2 * BUF_BYTES];
  const int tid = threadIdx.x;
  const int wv = tid >> 6, ln = tid & 63;
  const int lc = ln & 31, lh = ln >> 5;
  const int ch = blockIdx.x;   // 0..63 train chunk; XCD = (bx + 64*by)%8 = bx%8
  const int sb = blockIdx.y;   // 0..7  sample block of 512

  // hoisted sample fragments: bf[set][kchunk], lane = (col l&31, k-half l>>5), 32 B
  i32x8 bf[4][4];
  float nsv[4];
#pragma unroll
  for (int s = 0; s < 4; s++) {
    int samp = sb * 512 + wv * 128 + s * 32 + lc;
    nsv[s] = Snrm[samp];
#pragma unroll
    for (int kc = 0; kc < 4; kc++) {
      const char* p = (const char*)Sf8 + (size_t)samp * D_FEAT + kc * 64 + lh * 32;
      i32x4 blo = *(const i32x4*)p;
      i32x4 bhi = *(const i32x4*)(p + 16);
      i32x8 b;
      b[0] = blo[0]; b[1] = blo[1]; b[2] = blo[2]; b[3] = blo[3];
      b[4] = bhi[0]; b[5] = bhi[1]; b[6] = bhi[2]; b[7] = bhi[3];
      bf[s][kc] = b;
    }
  }

  const char* abase = (const char*)Tf8 + (size_t)ch * CHUNK_ROWS * D_FEAT;
  const char* nbase = (const char*)(Tnrm + (size_t)ch * CHUNK_ROWS);

  float b0[4], b1[4];
#pragma unroll
  for (int s = 0; s < 4; s++) { b0[s] = -3.0e38f; b1[s] = -3.0e38f; }

  // 9 uniform loads/wave: 8 A-regions (r = wv+4j) + 1 norm load (all waves same,
  // lanes 0-31 real data, lanes 32-63 write the 512-B pad -- benign identical race)
  auto stage = [&](int buf, int it) {
    const char* ab = abase + (size_t)it * ABYTES;
    char* bb = smem + buf * BUF_BYTES;
#pragma unroll
    for (int j = 0; j < 8; j++) {
      int r = wv + 4 * j;
      int at = r >> 3, kc = (r >> 1) & 3, h = r & 1;
      const char* src = ab + (at * 32 + lc) * D_FEAT + kc * 64 + lh * 32 + h * 16;
      __builtin_amdgcn_global_load_lds(
          (const __attribute__((address_space(1))) void*)src,
          (__attribute__((address_space(3))) void*)(bb + r * 1024), 16, 0, 0);
    }
    const char* nsrc = nbase + (size_t)it * ROWS_ITER * 4 + lc * 16;
    __builtin_amdgcn_global_load_lds(
        (const __attribute__((address_space(1))) void*)nsrc,
        (__attribute__((address_space(3))) void*)(bb + NORM_OFF), 16, 0, 0);
  };

  stage(0, 0);

  for (int it = 0; it < NITER; ++it) {
    const int cur = it & 1;
    if (it + 1 < NITER) {
      stage(cur ^ 1, it + 1);
      asm volatile("s_waitcnt vmcnt(9)" ::: "memory");  // own prev stage drained
    } else {
      asm volatile("s_waitcnt vmcnt(0)" ::: "memory");
    }
    __builtin_amdgcn_s_barrier();
    asm volatile("" ::: "memory");

    const char* lds = smem + cur * BUF_BYTES;
#pragma unroll
    for (int at = 0; at < 4; ++at) {
      f32x16 c[4];
#pragma unroll
      for (int s = 0; s < 4; s++)
#pragma unroll
        for (int r = 0; r < 16; r++) c[s][r] = 0.f;
#pragma unroll
      for (int kc = 0; kc < 4; kc++) {
        const char* rb = lds + (at * 8 + kc * 2) * 1024;
        i32x4 alo = *(const i32x4*)(rb + ln * 16);
        i32x4 ahi = *(const i32x4*)(rb + 1024 + ln * 16);
        i32x8 a;
        a[0] = alo[0]; a[1] = alo[1]; a[2] = alo[2]; a[3] = alo[3];
        a[4] = ahi[0]; a[5] = ahi[1]; a[6] = ahi[2]; a[7] = ahi[3];
#pragma unroll
        for (int s = 0; s < 4; s++)
          c[s] = __builtin_amdgcn_mfma_scale_f32_32x32x64_f8f6f4(
                     a, bf[s][kc], c[s], 0, 0, 0, 0x7F7F7F7F, 0, 0x7F7F7F7F);
      }
      // exact f32 train half-norms, broadcast reads (row = (r&3)+8*(r>>2)+4*lh)
      float nt[16];
#pragma unroll
      for (int r = 0; r < 16; r++)
        nt[r] = *(const float*)(lds + NORM_OFF + at * 128 + lh * 16 +
                                (r & 3) * 4 + (r >> 2) * 32);
#pragma unroll
      for (int s = 0; s < 4; s++)
#pragma unroll
        for (int r = 0; r < 16; r++) {
          float v = c[s][r] - nt[r];   // v = x.y - nt; top-2 largest
          b1[s] = __builtin_amdgcn_fmed3f(v, b0[s], b1[s]);
          b0[s] = fmaxf(v, b0[s]);
        }
    }
    asm volatile("s_waitcnt lgkmcnt(0)" ::: "memory");  // all ds_reads of buf retired
    __builtin_amdgcn_s_barrier();                       // before it is overwritten
    asm volatile("" ::: "memory");
  }

  // fold sample norm, then merge lanes l <-> l+32 (same col, complementary rows)
#pragma unroll
  for (int s = 0; s < 4; s++) {
    b0[s] -= nsv[s]; b1[s] -= nsv[s];
    float o0 = __shfl_xor(b0[s], 32), o1 = __shfl_xor(b1[s], 32);
    float t = fmaxf(b0[s], o0);
    b1[s] = fmaxf(__builtin_amdgcn_fmed3f(o0, b0[s], b1[s]), o1);
    b0[s] = t;
  }
  if (lh == 0) {
    int s0 = sb * 512 + wv * 128 + lc;
#pragma unroll
    for (int s = 0; s < 4; s++) {
      f32x2 p = {b0[s], b1[s]};
      partials[(size_t)ch * N_SAMP + s0 + s * 32] = p;
    }
  }
}

// ---------------- final merge: distances only ----------------
__global__ __launch_bounds__(128) void reduce_final(const f32x2* __restrict__ partials,
                                                    float* __restrict__ out) {
  int s = blockIdx.x * 128 + threadIdx.x;
  float b0 = -3.0e38f, b1 = -3.0e38f;
#pragma unroll 8
  for (int c = 0; c < NCHUNK; c++) {
    f32x2 p = partials[(size_t)c * N_SAMP + s];
    b1 = __builtin_amdgcn_fmed3f(p[0], b0, b1); b0 = fmaxf(p[0], b0);
    b1 = __builtin_amdgcn_fmed3f(p[1], b0, b1); b0 = fmaxf(p[1], b0);
  }
  out[2 * s]     = sqrtf(fmaxf(-2.0f * b0, 0.0f));
  out[2 * s + 1] = sqrtf(fmaxf(-2.0f * b1, 0.0f));
}

// ---------------- ratio: rescan out, idempotent ----------------
__global__ __launch_bounds__(256) void ratio_k(float* __restrict__ out) {
  __shared__ int wsum[4];
  int tid = threadIdx.x;
  int cnt = 0;
#pragma unroll
  for (int rep = 0; rep < 16; ++rep) {
    int s = rep * 256 + tid;
    cnt += (out[2 * s] < (1.0f / 3.0f) * out[2 * s + 1]) ? 1 : 0;
  }
#pragma unroll
  for (int m = 32; m; m >>= 1) cnt += __shfl_xor(cnt, m);
  if ((tid & 63) == 0) wsum[tid >> 6] = cnt;
  __syncthreads();
  if (tid == 0)
    out[2 * N_SAMP] = (float)(wsum[0] + wsum[1] + wsum[2] + wsum[3]) *
                      (1.0f / (float)N_SAMP);
}

extern "C" void kernel_launch(void* const* d_in, const int* in_sizes, int n_in,
                              void* d_out, int out_size, void* d_ws, size_t ws_size,
                              hipStream_t stream) {
  const float* Xs = (const float*)d_in[0];   // X_sample [4096][256]
  const float* Xt = (const float*)d_in[1];   // X_train  [65536][256]
  unsigned char* Tf8 = (unsigned char*)d_ws;                       // 16 MiB
  unsigned char* Sf8 = Tf8 + (size_t)N_TRAIN * D_FEAT;             // 1 MiB
  float* Tnrm = (float*)(Sf8 + (size_t)N_SAMP * D_FEAT);           // 256 KiB
  float* Snrm = Tnrm + N_TRAIN;                                    // 16 KiB
  f32x2* partials = (f32x2*)(Snrm + N_SAMP);                       // 2 MiB
  float* out = (float*)d_out;

  prep_fp8<<<N_TRAIN / 4, 256, 0, stream>>>(Xt, Tf8, Tnrm, N_TRAIN);
  prep_fp8<<<N_SAMP / 4, 256, 0, stream>>>(Xs, Sf8, Snrm, N_SAMP);
  topk_gemm<<<dim3(NCHUNK, N_SAMP / 512), 256, 0, stream>>>(Tf8, Tnrm, Sf8, Snrm, partials);
  reduce_final<<<N_SAMP / 128, 128, 0, stream>>>(partials, out);
  ratio_k<<<1, 256, 0, stream>>>(out);
}

// Round 8
// 164.775 us; speedup vs baseline: 3.7179x; 1.0244x over previous
//
#include <hip/hip_runtime.h>

typedef int    i32x4  __attribute__((ext_vector_type(4)));
typedef int    i32x8  __attribute__((ext_vector_type(8)));
typedef float  f32x4  __attribute__((ext_vector_type(4)));
typedef float  f32x16 __attribute__((ext_vector_type(16)));
typedef float  f32x2  __attribute__((ext_vector_type(2)));
typedef unsigned char u8x4 __attribute__((ext_vector_type(4)));

#define D_FEAT     256
#define N_SAMP     4096
#define N_TRAIN    65536
#define NCHUNK     64
#define CHUNK_ROWS (N_TRAIN / NCHUNK)       // 1024
#define ROWS_ITER  128
#define NITER      (CHUNK_ROWS / ROWS_ITER) // 8
#define ABYTES     (ROWS_ITER * D_FEAT)     // 32768 (A-tile fp8 bytes)
#define NORM_OFF   ABYTES                   // f32 neg-half-norms (512 used + 512 pad)
#define BUF_BYTES  (ABYTES + 1024)          // 33792; x2 bufs x2 blocks = 132 KiB/CU

// ---- fp32 -> OCP e4m3fn (RNE, subnormals, clamp 448) ----
__device__ __forceinline__ unsigned char f2fp8(float x) {
  unsigned u = __builtin_bit_cast(unsigned, x);
  unsigned s = (u >> 24) & 0x80u;
  unsigned mag = u & 0x7FFFFFFFu;
  if (mag >= 0x43E80000u) return (unsigned char)(s | 0x7E);  // >=452 -> 448
  unsigned e = mag >> 23;
  if (e >= 121u) {                       // |x| >= 2^-6: normal
    unsigned r = mag + 0x7FFFFu + ((mag >> 20) & 1u);        // RNE at bit 20
    if (r >= 0x43E80000u) return (unsigned char)(s | 0x7E);
    return (unsigned char)(s | (((r >> 23) - 120u) << 3) | ((r >> 20) & 7u));
  }
  float a = __builtin_bit_cast(float, mag) * 512.0f;         // subnormal step 2^-9
  unsigned m = (unsigned)(a + 0.5f);
  if (m >= 8u) return (unsigned char)(s | 0x08u);
  return (unsigned char)(s | m);
}

// ---------------- prep (merged): fp32 -> fp8 + signed half-norms ----------------
// Train rows (gid < N_TRAIN): Nrm = -||x||^2/2 (negated: used as accumulator init).
// Sample rows: Nrm = +||x||^2/2 (subtracted in gemm epilogue).
__global__ __launch_bounds__(256) void prep_fp8(const float* __restrict__ Xt,
                                                const float* __restrict__ Xs,
                                                unsigned char* __restrict__ Tf8,
                                                unsigned char* __restrict__ Sf8,
                                                float* __restrict__ Tnrm,
                                                float* __restrict__ Snrm) {
  int wv = threadIdx.x >> 6, ln = threadIdx.x & 63;
  int gid = blockIdx.x * 4 + wv;
  const float* X = Xt; unsigned char* F = Tf8; float* Nrm = Tnrm;
  float nsc = -0.5f; int row = gid;
  if (gid >= N_TRAIN) { row = gid - N_TRAIN; X = Xs; F = Sf8; Nrm = Snrm; nsc = 0.5f; }
  const float4* xr = (const float4*)(X + (size_t)row * D_FEAT);
  float4 v = xr[ln];
  float ss = v.x * v.x + v.y * v.y + v.z * v.z + v.w * v.w;
#pragma unroll
  for (int m = 32; m; m >>= 1) ss += __shfl_xor(ss, m);
  u8x4 o;
  o[0] = f2fp8(v.x); o[1] = f2fp8(v.y); o[2] = f2fp8(v.z); o[3] = f2fp8(v.w);
  ((u8x4*)(F + (size_t)row * D_FEAT))[ln] = o;
  if (ln == 0) Nrm[row] = nsc * ss;
}

// ---------------- main: MX-fp8 32x32x64 GEMM + online top-2 ----------------
// 256-thr block (4 waves), wave owns 128 samples = 4 register B-sets x 4 K-chunks.
// Accumulator INITIALIZED to -nt (negated train half-norm, from LDS f32x4
// broadcast) so MFMA output is x.y - nt directly -> epilogue = med3+max only.
// LDS: 128 rows x 256 B fp8 + 512 B norms, double-buffered; 1024-B regions in
// fragment order (region r: at=r>>3, kc=(r>>1)&3, h=r&1; lane l = row at*32+(l&31),
// bytes kc*64+(l>>5)*32+h*16). Proven 2-barrier template, 9 loads/wave, vmcnt(9).
__global__ __launch_bounds__(256, 2) void topk_gemm(const unsigned char* __restrict__ Tf8,
                                                    const float* __restrict__ Tnrm,
                                                    const unsigned char* __restrict__ Sf8,
                                                    const float* __restrict__ Snrm,
                                                    f32x2* __restrict__ partials) {
  __shared__ __attribute__((aligned(16))) char smem[2 * BUF_BYTES];
  const int tid = threadIdx.x;
  const int wv = tid >> 6, ln = tid & 63;
  const int lc = ln & 31, lh = ln >> 5;
  const int ch = blockIdx.x;   // 0..63 train chunk; XCD = bx%8 -> chunk L2 locality
  const int sb = blockIdx.y;   // 0..7  sample block of 512

  // hoisted sample fragments: bf[set][kchunk], lane = (col l&31, k-half l>>5), 32 B
  i32x8 bf[4][4];
  float nsv[4];
#pragma unroll
  for (int s = 0; s < 4; s++) {
    int samp = sb * 512 + wv * 128 + s * 32 + lc;
    nsv[s] = Snrm[samp];
#pragma unroll
    for (int kc = 0; kc < 4; kc++) {
      const char* p = (const char*)Sf8 + (size_t)samp * D_FEAT + kc * 64 + lh * 32;
      i32x4 blo = *(const i32x4*)p;
      i32x4 bhi = *(const i32x4*)(p + 16);
      bf[s][kc] = __builtin_shufflevector(blo, bhi, 0, 1, 2, 3, 4, 5, 6, 7);
    }
  }

  const char* abase = (const char*)Tf8 + (size_t)ch * CHUNK_ROWS * D_FEAT;
  const char* nbase = (const char*)(Tnrm + (size_t)ch * CHUNK_ROWS);

  float b0[4], b1[4];
#pragma unroll
  for (int s = 0; s < 4; s++) { b0[s] = -3.0e38f; b1[s] = -3.0e38f; }

  // 9 uniform loads/wave: 8 A-regions (r = wv+4j) + 1 norm load (all waves same
  // dest; lanes 32-63 fill the 512-B pad -- benign identical race)
  auto stage = [&](int buf, int it) {
    const char* ab = abase + (size_t)it * ABYTES;
    char* bb = smem + buf * BUF_BYTES;
#pragma unroll
    for (int j = 0; j < 8; j++) {
      int r = wv + 4 * j;
      int at = r >> 3, kc = (r >> 1) & 3, h = r & 1;
      const char* src = ab + (at * 32 + lc) * D_FEAT + kc * 64 + lh * 32 + h * 16;
      __builtin_amdgcn_global_load_lds(
          (const __attribute__((address_space(1))) void*)src,
          (__attribute__((address_space(3))) void*)(bb + r * 1024), 16, 0, 0);
    }
    const char* nsrc = nbase + (size_t)it * ROWS_ITER * 4 + lc * 16;
    __builtin_amdgcn_global_load_lds(
        (const __attribute__((address_space(1))) void*)nsrc,
        (__attribute__((address_space(3))) void*)(bb + NORM_OFF), 16, 0, 0);
  };

  stage(0, 0);

  for (int it = 0; it < NITER; ++it) {
    const int cur = it & 1;
    if (it + 1 < NITER) {
      stage(cur ^ 1, it + 1);
      asm volatile("s_waitcnt vmcnt(9)" ::: "memory");  // own prev stage drained
    } else {
      asm volatile("s_waitcnt vmcnt(0)" ::: "memory");
    }
    __builtin_amdgcn_s_barrier();
    asm volatile("" ::: "memory");

    const char* lds = smem + cur * BUF_BYTES;
#pragma unroll
    for (int at = 0; at < 4; ++at) {
      // negated train half-norms, broadcast f32x4 reads:
      // MFMA row(r) = (r&3) + 8*(r>>2) + 4*lh  ->  ntv[r>>2][r&3]
      f32x4 ntv[4];
#pragma unroll
      for (int q = 0; q < 4; q++)
        ntv[q] = *(const f32x4*)(lds + NORM_OFF + at * 128 + lh * 16 + q * 32);
      f32x16 c[4];
#pragma unroll
      for (int s = 0; s < 4; s++)
#pragma unroll
        for (int r = 0; r < 16; r++) c[s][r] = ntv[r >> 2][r & 3];
      __builtin_amdgcn_s_setprio(1);
#pragma unroll
      for (int kc = 0; kc < 4; kc++) {
        const char* rb = lds + (at * 8 + kc * 2) * 1024;
        i32x4 alo = *(const i32x4*)(rb + ln * 16);
        i32x4 ahi = *(const i32x4*)(rb + 1024 + ln * 16);
        i32x8 a = __builtin_shufflevector(alo, ahi, 0, 1, 2, 3, 4, 5, 6, 7);
#pragma unroll
        for (int s = 0; s < 4; s++)
          c[s] = __builtin_amdgcn_mfma_scale_f32_32x32x64_f8f6f4(
                     a, bf[s][kc], c[s], 0, 0, 0, 0x7F7F7F7F, 0, 0x7F7F7F7F);
      }
      __builtin_amdgcn_s_setprio(0);
      // c = x.y - nt; online top-2 (largest), 2 VALU per value
#pragma unroll
      for (int s = 0; s < 4; s++)
#pragma unroll
        for (int r = 0; r < 16; r++) {
          float v = c[s][r];
          b1[s] = __builtin_amdgcn_fmed3f(v, b0[s], b1[s]);
          b0[s] = fmaxf(v, b0[s]);
        }
    }
    asm volatile("s_waitcnt lgkmcnt(0)" ::: "memory");  // all ds_reads of buf retired
    __builtin_amdgcn_s_barrier();                       // before it is overwritten
    asm volatile("" ::: "memory");
  }

  // fold sample norm, then merge lanes l <-> l+32 (same col, complementary rows)
#pragma unroll
  for (int s = 0; s < 4; s++) {
    b0[s] -= nsv[s]; b1[s] -= nsv[s];
    float o0 = __shfl_xor(b0[s], 32), o1 = __shfl_xor(b1[s], 32);
    float t = fmaxf(b0[s], o0);
    b1[s] = fmaxf(__builtin_amdgcn_fmed3f(o0, b0[s], b1[s]), o1);
    b0[s] = t;
  }
  if (lh == 0) {
    int s0 = sb * 512 + wv * 128 + lc;
#pragma unroll
    for (int s = 0; s < 4; s++) {
      f32x2 p = {b0[s], b1[s]};
      partials[(size_t)ch * N_SAMP + s0 + s * 32] = p;
    }
  }
}

// ---------------- final merge: distances only ----------------
__global__ __launch_bounds__(128) void reduce_final(const f32x2* __restrict__ partials,
                                                    float* __restrict__ out) {
  int s = blockIdx.x * 128 + threadIdx.x;
  float b0 = -3.0e38f, b1 = -3.0e38f;
#pragma unroll 8
  for (int c = 0; c < NCHUNK; c++) {
    f32x2 p = partials[(size_t)c * N_SAMP + s];
    b1 = __builtin_amdgcn_fmed3f(p[0], b0, b1); b0 = fmaxf(p[0], b0);
    b1 = __builtin_amdgcn_fmed3f(p[1], b0, b1); b0 = fmaxf(p[1], b0);
  }
  out[2 * s]     = sqrtf(fmaxf(-2.0f * b0, 0.0f));
  out[2 * s + 1] = sqrtf(fmaxf(-2.0f * b1, 0.0f));
}

// ---------------- ratio: rescan out, idempotent ----------------
__global__ __launch_bounds__(256) void ratio_k(float* __restrict__ out) {
  __shared__ int wsum[4];
  int tid = threadIdx.x;
  int cnt = 0;
#pragma unroll
  for (int rep = 0; rep < 16; ++rep) {
    int s = rep * 256 + tid;
    cnt += (out[2 * s] < (1.0f / 3.0f) * out[2 * s + 1]) ? 1 : 0;
  }
#pragma unroll
  for (int m = 32; m; m >>= 1) cnt += __shfl_xor(cnt, m);
  if ((tid & 63) == 0) wsum[tid >> 6] = cnt;
  __syncthreads();
  if (tid == 0)
    out[2 * N_SAMP] = (float)(wsum[0] + wsum[1] + wsum[2] + wsum[3]) *
                      (1.0f / (float)N_SAMP);
}

extern "C" void kernel_launch(void* const* d_in, const int* in_sizes, int n_in,
                              void* d_out, int out_size, void* d_ws, size_t ws_size,
                              hipStream_t stream) {
  const float* Xs = (const float*)d_in[0];   // X_sample [4096][256]
  const float* Xt = (const float*)d_in[1];   // X_train  [65536][256]
  unsigned char* Tf8 = (unsigned char*)d_ws;                       // 16 MiB
  unsigned char* Sf8 = Tf8 + (size_t)N_TRAIN * D_FEAT;             // 1 MiB
  float* Tnrm = (float*)(Sf8 + (size_t)N_SAMP * D_FEAT);           // 256 KiB (negated)
  float* Snrm = Tnrm + N_TRAIN;                                    // 16 KiB
  f32x2* partials = (f32x2*)(Snrm + N_SAMP);                       // 2 MiB
  float* out = (float*)d_out;

  prep_fp8<<<(N_TRAIN + N_SAMP) / 4, 256, 0, stream>>>(Xt, Xs, Tf8, Sf8, Tnrm, Snrm);
  topk_gemm<<<dim3(NCHUNK, N_SAMP / 512), 256, 0, stream>>>(Tf8, Tnrm, Sf8, Snrm, partials);
  reduce_final<<<N_SAMP / 128, 128, 0, stream>>>(partials, out);
  ratio_k<<<1, 256, 0, stream>>>(out);
}

// Round 9
// 163.744 us; speedup vs baseline: 3.7413x; 1.0063x over previous
//
#include <hip/hip_runtime.h>

typedef int    i32x4  __attribute__((ext_vector_type(4)));
typedef int    i32x8  __attribute__((ext_vector_type(8)));
typedef float  f32x4  __attribute__((ext_vector_type(4)));
typedef float  f32x16 __attribute__((ext_vector_type(16)));
typedef float  f32x2  __attribute__((ext_vector_type(2)));
typedef unsigned char u8x4 __attribute__((ext_vector_type(4)));

#define D_FEAT     256
#define N_SAMP     4096
#define N_TRAIN    65536
#define NCHUNK     64
#define CHUNK_ROWS (N_TRAIN / NCHUNK)       // 1024
#define ROWS_ITER  128
#define NITER      (CHUNK_ROWS / ROWS_ITER) // 8
#define ABYTES     (ROWS_ITER * D_FEAT)     // 32768 (A-tile fp8 bytes)
#define NORM_OFF   ABYTES                   // f32 neg-half-norms (512 used + 512 pad)
#define BUF_BYTES  (ABYTES + 1024)          // 33792; x2 bufs x2 blocks = 132 KiB/CU

// ---- fp32 -> OCP e4m3fn (RNE, subnormals, clamp 448) ----
__device__ __forceinline__ unsigned char f2fp8(float x) {
  unsigned u = __builtin_bit_cast(unsigned, x);
  unsigned s = (u >> 24) & 0x80u;
  unsigned mag = u & 0x7FFFFFFFu;
  if (mag >= 0x43E80000u) return (unsigned char)(s | 0x7E);  // >=452 -> 448
  unsigned e = mag >> 23;
  if (e >= 121u) {                       // |x| >= 2^-6: normal
    unsigned r = mag + 0x7FFFFu + ((mag >> 20) & 1u);        // RNE at bit 20
    if (r >= 0x43E80000u) return (unsigned char)(s | 0x7E);
    return (unsigned char)(s | (((r >> 23) - 120u) << 3) | ((r >> 20) & 7u));
  }
  float a = __builtin_bit_cast(float, mag) * 512.0f;         // subnormal step 2^-9
  unsigned m = (unsigned)(a + 0.5f);
  if (m >= 8u) return (unsigned char)(s | 0x08u);
  return (unsigned char)(s | m);
}

// ---------------- prep (merged): fp32 -> fp8 + signed half-norms ----------------
// Train rows (gid < N_TRAIN): Nrm = -||x||^2/2 (negated: used as accumulator init).
// Sample rows: Nrm = +||x||^2/2 (subtracted in gemm epilogue).
__global__ __launch_bounds__(256) void prep_fp8(const float* __restrict__ Xt,
                                                const float* __restrict__ Xs,
                                                unsigned char* __restrict__ Tf8,
                                                unsigned char* __restrict__ Sf8,
                                                float* __restrict__ Tnrm,
                                                float* __restrict__ Snrm) {
  int wv = threadIdx.x >> 6, ln = threadIdx.x & 63;
  int gid = blockIdx.x * 4 + wv;
  const float* X = Xt; unsigned char* F = Tf8; float* Nrm = Tnrm;
  float nsc = -0.5f; int row = gid;
  if (gid >= N_TRAIN) { row = gid - N_TRAIN; X = Xs; F = Sf8; Nrm = Snrm; nsc = 0.5f; }
  const float4* xr = (const float4*)(X + (size_t)row * D_FEAT);
  float4 v = xr[ln];
  float ss = v.x * v.x + v.y * v.y + v.z * v.z + v.w * v.w;
#pragma unroll
  for (int m = 32; m; m >>= 1) ss += __shfl_xor(ss, m);
  u8x4 o;
  o[0] = f2fp8(v.x); o[1] = f2fp8(v.y); o[2] = f2fp8(v.z); o[3] = f2fp8(v.w);
  ((u8x4*)(F + (size_t)row * D_FEAT))[ln] = o;
  if (ln == 0) Nrm[row] = nsc * ss;
}

// ---------------- main: MX-fp8 32x32x64 GEMM + online top-2 ----------------
// 256-thr block (4 waves), wave owns 128 samples = 4 register B-sets x 4 K-chunks.
// Accumulator INITIALIZED to -nt so MFMA yields x.y - nt; epilogue = med3+max.
// LDS layout / template identical to round 8 (proven). NEW: anti-convoy stagger --
// each CU hosts 2 blocks (ids 256 apart, i.e. by^4) dispatched simultaneously with
// identical periods; a one-time s_sleep on one partner anti-phases the pair so
// one block's MFMA burst overlaps the other's epilogue/stage phase permanently.
__global__ __launch_bounds__(256, 2) void topk_gemm(const unsigned char* __restrict__ Tf8,
                                                    const float* __restrict__ Tnrm,
                                                    const unsigned char* __restrict__ Sf8,
                                                    const float* __restrict__ Snrm,
                                                    f32x2* __restrict__ partials) {
  __shared__ __attribute__((aligned(16))) char smem[2 * BUF_BYTES];
  const int tid = threadIdx.x;
  const int wv = tid >> 6, ln = tid & 63;
  const int lc = ln & 31, lh = ln >> 5;
  const int ch = blockIdx.x;   // 0..63 train chunk; XCD = bx%8 -> chunk L2 locality
  const int sb = blockIdx.y;   // 0..7  sample block of 512

  // hoisted sample fragments: bf[set][kchunk], lane = (col l&31, k-half l>>5), 32 B
  i32x8 bf[4][4];
  float nsv[4];
#pragma unroll
  for (int s = 0; s < 4; s++) {
    int samp = sb * 512 + wv * 128 + s * 32 + lc;
    nsv[s] = Snrm[samp];
#pragma unroll
    for (int kc = 0; kc < 4; kc++) {
      const char* p = (const char*)Sf8 + (size_t)samp * D_FEAT + kc * 64 + lh * 32;
      i32x4 blo = *(const i32x4*)p;
      i32x4 bhi = *(const i32x4*)(p + 16);
      bf[s][kc] = __builtin_shufflevector(blo, bhi, 0, 1, 2, 3, 4, 5, 6, 7);
    }
  }

  const char* abase = (const char*)Tf8 + (size_t)ch * CHUNK_ROWS * D_FEAT;
  const char* nbase = (const char*)(Tnrm + (size_t)ch * CHUNK_ROWS);

  float b0[4], b1[4];
#pragma unroll
  for (int s = 0; s < 4; s++) { b0[s] = -3.0e38f; b1[s] = -3.0e38f; }

  // 9 uniform loads/wave: 8 A-regions (r = wv+4j) + 1 norm load (all waves same
  // dest; lanes 32-63 fill the 512-B pad -- benign identical race)
  auto stage = [&](int buf, int it) {
    const char* ab = abase + (size_t)it * ABYTES;
    char* bb = smem + buf * BUF_BYTES;
#pragma unroll
    for (int j = 0; j < 8; j++) {
      int r = wv + 4 * j;
      int at = r >> 3, kc = (r >> 1) & 3, h = r & 1;
      const char* src = ab + (at * 32 + lc) * D_FEAT + kc * 64 + lh * 32 + h * 16;
      __builtin_amdgcn_global_load_lds(
          (const __attribute__((address_space(1))) void*)src,
          (__attribute__((address_space(3))) void*)(bb + r * 1024), 16, 0, 0);
    }
    const char* nsrc = nbase + (size_t)it * ROWS_ITER * 4 + lc * 16;
    __builtin_amdgcn_global_load_lds(
        (const __attribute__((address_space(1))) void*)nsrc,
        (__attribute__((address_space(3))) void*)(bb + NORM_OFF), 16, 0, 0);
  };

  stage(0, 0);

  // anti-convoy: one partner of each same-CU block pair sleeps ~4k cycles once
  if ((sb >> 2) & 1) {
    asm volatile("s_sleep 32\n\ts_sleep 32" ::: "memory");
  }

  for (int it = 0; it < NITER; ++it) {
    const int cur = it & 1;
    if (it + 1 < NITER) {
      stage(cur ^ 1, it + 1);
      asm volatile("s_waitcnt vmcnt(9)" ::: "memory");  // own prev stage drained
    } else {
      asm volatile("s_waitcnt vmcnt(0)" ::: "memory");
    }
    __builtin_amdgcn_s_barrier();
    asm volatile("" ::: "memory");

    const char* lds = smem + cur * BUF_BYTES;
#pragma unroll
    for (int at = 0; at < 4; ++at) {
      // negated train half-norms, broadcast f32x4 reads:
      // MFMA row(r) = (r&3) + 8*(r>>2) + 4*lh  ->  ntv[r>>2][r&3]
      f32x4 ntv[4];
#pragma unroll
      for (int q = 0; q < 4; q++)
        ntv[q] = *(const f32x4*)(lds + NORM_OFF + at * 128 + lh * 16 + q * 32);
      f32x16 c[4];
#pragma unroll
      for (int s = 0; s < 4; s++)
#pragma unroll
        for (int r = 0; r < 16; r++) c[s][r] = ntv[r >> 2][r & 3];
      __builtin_amdgcn_s_setprio(1);
#pragma unroll
      for (int kc = 0; kc < 4; kc++) {
        const char* rb = lds + (at * 8 + kc * 2) * 1024;
        i32x4 alo = *(const i32x4*)(rb + ln * 16);
        i32x4 ahi = *(const i32x4*)(rb + 1024 + ln * 16);
        i32x8 a = __builtin_shufflevector(alo, ahi, 0, 1, 2, 3, 4, 5, 6, 7);
#pragma unroll
        for (int s = 0; s < 4; s++)
          c[s] = __builtin_amdgcn_mfma_scale_f32_32x32x64_f8f6f4(
                     a, bf[s][kc], c[s], 0, 0, 0, 0x7F7F7F7F, 0, 0x7F7F7F7F);
      }
      __builtin_amdgcn_s_setprio(0);
      // c = x.y - nt; online top-2 (largest), 2 VALU per value
#pragma unroll
      for (int s = 0; s < 4; s++)
#pragma unroll
        for (int r = 0; r < 16; r++) {
          float v = c[s][r];
          b1[s] = __builtin_amdgcn_fmed3f(v, b0[s], b1[s]);
          b0[s] = fmaxf(v, b0[s]);
        }
    }
    asm volatile("s_waitcnt lgkmcnt(0)" ::: "memory");  // all ds_reads of buf retired
    __builtin_amdgcn_s_barrier();                       // before it is overwritten
    asm volatile("" ::: "memory");
  }

  // fold sample norm, then merge lanes l <-> l+32 (same col, complementary rows)
#pragma unroll
  for (int s = 0; s < 4; s++) {
    b0[s] -= nsv[s]; b1[s] -= nsv[s];
    float o0 = __shfl_xor(b0[s], 32), o1 = __shfl_xor(b1[s], 32);
    float t = fmaxf(b0[s], o0);
    b1[s] = fmaxf(__builtin_amdgcn_fmed3f(o0, b0[s], b1[s]), o1);
    b0[s] = t;
  }
  if (lh == 0) {
    int s0 = sb * 512 + wv * 128 + lc;
#pragma unroll
    for (int s = 0; s < 4; s++) {
      f32x2 p = {b0[s], b1[s]};
      partials[(size_t)ch * N_SAMP + s0 + s * 32] = p;
    }
  }
}

// ---------------- final merge: distances only ----------------
__global__ __launch_bounds__(128) void reduce_final(const f32x2* __restrict__ partials,
                                                    float* __restrict__ out) {
  int s = blockIdx.x * 128 + threadIdx.x;
  float b0 = -3.0e38f, b1 = -3.0e38f;
#pragma unroll 8
  for (int c = 0; c < NCHUNK; c++) {
    f32x2 p = partials[(size_t)c * N_SAMP + s];
    b1 = __builtin_amdgcn_fmed3f(p[0], b0, b1); b0 = fmaxf(p[0], b0);
    b1 = __builtin_amdgcn_fmed3f(p[1], b0, b1); b0 = fmaxf(p[1], b0);
  }
  out[2 * s]     = sqrtf(fmaxf(-2.0f * b0, 0.0f));
  out[2 * s + 1] = sqrtf(fmaxf(-2.0f * b1, 0.0f));
}

// ---------------- ratio: rescan out, idempotent ----------------
__global__ __launch_bounds__(256) void ratio_k(float* __restrict__ out) {
  __shared__ int wsum[4];
  int tid = threadIdx.x;
  int cnt = 0;
#pragma unroll
  for (int rep = 0; rep < 16; ++rep) {
    int s = rep * 256 + tid;
    cnt += (out[2 * s] < (1.0f / 3.0f) * out[2 * s + 1]) ? 1 : 0;
  }
#pragma unroll
  for (int m = 32; m; m >>= 1) cnt += __shfl_xor(cnt, m);
  if ((tid & 63) == 0) wsum[tid >> 6] = cnt;
  __syncthreads();
  if (tid == 0)
    out[2 * N_SAMP] = (float)(wsum[0] + wsum[1] + wsum[2] + wsum[3]) *
                      (1.0f / (float)N_SAMP);
}

extern "C" void kernel_launch(void* const* d_in, const int* in_sizes, int n_in,
                              void* d_out, int out_size, void* d_ws, size_t ws_size,
                              hipStream_t stream) {
  const float* Xs = (const float*)d_in[0];   // X_sample [4096][256]
  const float* Xt = (const float*)d_in[1];   // X_train  [65536][256]
  unsigned char* Tf8 = (unsigned char*)d_ws;                       // 16 MiB
  unsigned char* Sf8 = Tf8 + (size_t)N_TRAIN * D_FEAT;             // 1 MiB
  float* Tnrm = (float*)(Sf8 + (size_t)N_SAMP * D_FEAT);           // 256 KiB (negated)
  float* Snrm = Tnrm + N_TRAIN;                                    // 16 KiB
  f32x2* partials = (f32x2*)(Snrm + N_SAMP);                       // 2 MiB
  float* out = (float*)d_out;

  prep_fp8<<<(N_TRAIN + N_SAMP) / 4, 256, 0, stream>>>(Xt, Xs, Tf8, Sf8, Tnrm, Snrm);
  topk_gemm<<<dim3(NCHUNK, N_SAMP / 512), 256, 0, stream>>>(Tf8, Tnrm, Sf8, Snrm, partials);
  reduce_final<<<N_SAMP / 128, 128, 0, stream>>>(partials, out);
  ratio_k<<<1, 256, 0, stream>>>(out);
}